// Round 1
// baseline (699.428 us; speedup 1.0000x reference)
//
#include <hip/hip_runtime.h>
#include <cstdint>
#include <cstddef>

#define B    8
#define SEQ  2048
#define H    4
#define DKN  5
#define DIM  20
#define DP   8        // padded head dim (32B rows)
#define KTILE 256
#define QTILE 256

// ws layout (floats):
//   proj: 9 tensors [(t*3+x)][b][h][s][DP]   t: 0=Q-role(W0) 1=K-role(W1) 2=V-role(W2), x: 0=q 1=k 2=v
//   pre : 6 tensors [p][b][h][s][DKN]        per-pair normalized attention outputs

static __device__ __forceinline__ size_t proj_off(int t, int x, int b, int h) {
    return ((size_t)((t * 3 + x) * B + b) * H + h) * (size_t)SEQ * DP;
}

__global__ __launch_bounds__(256) void proj_kernel(
    const float* __restrict__ q, const float* __restrict__ k, const float* __restrict__ v,
    const float* __restrict__ W0, const float* __restrict__ b0,
    const float* __restrict__ W1, const float* __restrict__ b1,
    const float* __restrict__ W2, const float* __restrict__ b2,
    float* __restrict__ proj)
{
    __shared__ float Ws[3][DIM * DIM];
    __shared__ float bs[3][DIM];
    int tid = threadIdx.x;
    for (int i = tid; i < DIM * DIM; i += 256) {
        Ws[0][i] = W0[i]; Ws[1][i] = W1[i]; Ws[2][i] = W2[i];
    }
    if (tid < DIM) { bs[0][tid] = b0[tid]; bs[1][tid] = b1[tid]; bs[2][tid] = b2[tid]; }
    __syncthreads();

    int g   = blockIdx.x * 256 + tid;      // 3*B*SEQ = 49152 exactly
    int x   = g / (B * SEQ);
    int rem = g - x * (B * SEQ);
    int bb  = rem / SEQ;
    int s   = rem - bb * SEQ;

    const float* src = (x == 0 ? q : (x == 1 ? k : v)) + (size_t)(bb * SEQ + s) * DIM;
    float xr[DIM];
    #pragma unroll
    for (int i = 0; i < DIM; ++i) xr[i] = src[i];

    for (int t = 0; t < 3; ++t) {
        for (int h = 0; h < H; ++h) {
            float y[DKN];
            #pragma unroll
            for (int dd = 0; dd < DKN; ++dd) {
                int j = h * DKN + dd;
                float acc = bs[t][j];
                #pragma unroll
                for (int i = 0; i < DIM; ++i) acc += xr[i] * Ws[t][j * DIM + i];
                y[dd] = acc;
            }
            float* dst = proj + proj_off(t, x, bb, h) + (size_t)s * DP;
            ((float4*)dst)[0] = make_float4(y[0], y[1], y[2], y[3]);
            ((float4*)dst)[1] = make_float4(y[4], 0.f, 0.f, 0.f);
        }
    }
}

__global__ __launch_bounds__(256) void attn_kernel(
    const float* __restrict__ proj, const int* __restrict__ mask,
    float* __restrict__ pre)
{
    // blockIdx.x linear over (p, b, h, qt): 6*8*4*8 = 1536
    int lin = blockIdx.x;
    int qt  = lin & 7;  lin >>= 3;
    int h   = lin & 3;  lin >>= 2;
    int b   = lin & 7;  lin >>= 3;
    int p   = lin;                       // 0..5
    int a   = (0x212010 >> (4 * p)) & 0xF;   // Q source
    int bbs = (0x120201 >> (4 * p)) & 0xF;   // K/V source

    const float* Qb = proj + proj_off(0, a,   b, h);
    const float* Kb = proj + proj_off(1, bbs, b, h);
    const float* Vb = proj + proj_off(2, bbs, b, h);
    const int*  mrow = mask + b * SEQ;

    __shared__ float Ks[KTILE][DP];
    __shared__ float Vs[KTILE][DP];
    __shared__ int   Ms[KTILE];

    int tid = threadIdx.x;
    int sq  = qt * QTILE + tid;

    float4 q0 = ((const float4*)(Qb + (size_t)sq * DP))[0];
    float  q4 = Qb[(size_t)sq * DP + 4];

    float m = -1e30f, l = 0.f;
    float o0 = 0.f, o1 = 0.f, o2 = 0.f, o3 = 0.f, o4 = 0.f;
    const float scale = 0.44721359549995793f;   // 1/sqrt(5)

    for (int kt = 0; kt < SEQ; kt += KTILE) {
        __syncthreads();
        {
            const float4* sk = (const float4*)(Kb + (size_t)(kt + tid) * DP);
            ((float4*)Ks[tid])[0] = sk[0];
            ((float4*)Ks[tid])[1] = sk[1];
            const float4* sv = (const float4*)(Vb + (size_t)(kt + tid) * DP);
            ((float4*)Vs[tid])[0] = sv[0];
            ((float4*)Vs[tid])[1] = sv[1];
            Ms[tid] = mrow[kt + tid];
        }
        __syncthreads();

        #pragma unroll 4
        for (int kk = 0; kk < KTILE; ++kk) {
            float4 k0 = ((const float4*)Ks[kk])[0];
            float  k4 = Ks[kk][4];
            float  s  = q0.x * k0.x + q0.y * k0.y + q0.z * k0.z + q0.w * k0.w + q4 * k4;
            s *= scale;
            s = Ms[kk] ? s : -1e9f;

            float mn    = fmaxf(m, s);
            float alpha = __expf(m - mn);
            float pe    = __expf(s - mn);
            l = l * alpha + pe;

            float4 v0 = ((const float4*)Vs[kk])[0];
            float  v4 = Vs[kk][4];
            o0 = o0 * alpha + pe * v0.x;
            o1 = o1 * alpha + pe * v0.y;
            o2 = o2 * alpha + pe * v0.z;
            o3 = o3 * alpha + pe * v0.w;
            o4 = o4 * alpha + pe * v4;
            m = mn;
        }
    }

    float inv = 1.0f / l;
    float* dst = pre + (((size_t)p * B + b) * H + h) * (size_t)SEQ * DKN + (size_t)sq * DKN;
    dst[0] = o0 * inv; dst[1] = o1 * inv; dst[2] = o2 * inv;
    dst[3] = o3 * inv; dst[4] = o4 * inv;
}

__global__ __launch_bounds__(256) void final_kernel(
    const float* __restrict__ pre,
    const float* __restrict__ W3, const float* __restrict__ b3,
    float* __restrict__ out)
{
    __shared__ float Ws[DIM * DIM];
    __shared__ float bs[DIM];
    int tid = threadIdx.x;
    for (int i = tid; i < DIM * DIM; i += 256) Ws[i] = W3[i];
    if (tid < DIM) bs[tid] = b3[tid];
    __syncthreads();

    int g = blockIdx.x * 256 + tid;      // B*SEQ = 16384 exactly
    int b = g / SEQ;
    int s = g - b * SEQ;

    float x[DIM];
    #pragma unroll
    for (int i = 0; i < DIM; ++i) x[i] = 0.f;

    for (int p = 0; p < 6; ++p) {
        #pragma unroll
        for (int h = 0; h < H; ++h) {
            const float* src = pre + (((size_t)p * B + b) * H + h) * (size_t)SEQ * DKN
                                   + (size_t)s * DKN;
            #pragma unroll
            for (int d = 0; d < DKN; ++d) x[h * DKN + d] += src[d];
        }
    }

    float* dst = out + (size_t)(b * SEQ + s) * DIM;
    for (int j = 0; j < DIM; ++j) {
        float acc = bs[j];
        #pragma unroll
        for (int i = 0; i < DIM; ++i) acc += x[i] * Ws[j * DIM + i];
        dst[j] = acc;
    }
}

extern "C" void kernel_launch(void* const* d_in, const int* in_sizes, int n_in,
                              void* d_out, int out_size, void* d_ws, size_t ws_size,
                              hipStream_t stream) {
    const float* q    = (const float*)d_in[0];
    const float* k    = (const float*)d_in[1];
    const float* v    = (const float*)d_in[2];
    const int*   mask = (const int*)d_in[3];
    const float* W0 = (const float*)d_in[4];  const float* b0 = (const float*)d_in[5];
    const float* W1 = (const float*)d_in[6];  const float* b1 = (const float*)d_in[7];
    const float* W2 = (const float*)d_in[8];  const float* b2 = (const float*)d_in[9];
    const float* W3 = (const float*)d_in[10]; const float* b3 = (const float*)d_in[11];

    float* proj = (float*)d_ws;                                   // 9*B*H*SEQ*DP floats
    float* pre  = proj + (size_t)9 * B * H * SEQ * DP;            // 6*B*H*SEQ*DKN floats
    float* out  = (float*)d_out;

    proj_kernel<<<dim3(3 * B * SEQ / 256), dim3(256), 0, stream>>>(
        q, k, v, W0, b0, W1, b1, W2, b2, proj);
    attn_kernel<<<dim3(6 * B * H * (SEQ / QTILE)), dim3(256), 0, stream>>>(
        proj, mask, pre);
    final_kernel<<<dim3(B * SEQ / 256), dim3(256), 0, stream>>>(
        pre, W3, b3, out);
}

// Round 2
// 253.762 us; speedup vs baseline: 2.7562x; 2.7562x over previous
//
#include <hip/hip_runtime.h>
#include <cstdint>
#include <cstddef>

#define B    8
#define SEQ  2048
#define H    4
#define DKN  5
#define DIM  20
#define DP   8        // padded head dim (32B rows): [y0..y4, bias, 0, 0]
#define KT   128      // key tile
#define NEG_BIG (-3e38f)

typedef float v2f __attribute__((ext_vector_type(2)));

// exp2 (hardware v_exp_f32). Q is pre-scaled by scale*log2(e) so scores are in log2 domain.
#if __has_builtin(__builtin_amdgcn_exp2f)
#define EXP2(x) __builtin_amdgcn_exp2f(x)
#else
#define EXP2(x) __expf((x) * 0.6931471805599453f)
#endif

// ws layout (floats):
//   proj: 9 tensors [(t*3+x)][b][h][s][DP]  t: 0=Q-role(W0,pre-scaled,bias=1) 1=K-role(W1) 2=V-role(W2)
//   pre : 6 tensors [p][b][h][s][DKN]
//   idx : [B][SEQ] int  (compacted valid-key indices, stable order)
//   meta: [B] int       (valid-key count)

static __device__ __forceinline__ size_t proj_off(int t, int x, int b, int h) {
    return ((size_t)((t * 3 + x) * B + b) * H + h) * (size_t)SEQ * DP;
}

// ---- compaction: per batch, stable list of key positions with mask!=0 ----
__global__ __launch_bounds__(64) void compact_kernel(
    const int* __restrict__ mask, int* __restrict__ idx, int* __restrict__ meta)
{
    int b = blockIdx.x, lane = threadIdx.x;
    const int* m = mask + b * SEQ;
    int* out = idx + b * SEQ;
    int base = 0;
    #pragma unroll 4
    for (int c = 0; c < SEQ; c += 64) {
        int v = m[c + lane];
        unsigned long long bal = __ballot(v != 0);
        int pre = __popcll(bal & ((1ull << lane) - 1ull));
        if (v) out[base + pre] = c + lane;
        base += (int)__popcll(bal);
    }
    if (lane == 0) meta[b] = base;
}

__global__ __launch_bounds__(256) void proj_kernel(
    const float* __restrict__ q, const float* __restrict__ k, const float* __restrict__ v,
    const float* __restrict__ W0, const float* __restrict__ b0,
    const float* __restrict__ W1, const float* __restrict__ b1,
    const float* __restrict__ W2, const float* __restrict__ b2,
    float* __restrict__ proj)
{
    __shared__ float Ws[3][DIM * DIM];
    __shared__ float bs[3][DIM];
    int tid = threadIdx.x;
    for (int i = tid; i < DIM * DIM; i += 256) {
        Ws[0][i] = W0[i]; Ws[1][i] = W1[i]; Ws[2][i] = W2[i];
    }
    if (tid < DIM) { bs[0][tid] = b0[tid]; bs[1][tid] = b1[tid]; bs[2][tid] = b2[tid]; }
    __syncthreads();

    int g   = blockIdx.x * 256 + tid;      // 3*B*SEQ = 49152 exactly
    int x   = g / (B * SEQ);
    int rem = g - x * (B * SEQ);
    int bb  = rem / SEQ;
    int s   = rem - bb * SEQ;

    // scale/sqrt(DK) folded with log2(e) so attn can use raw v_exp_f32 (2^x)
    const float QSC = 0.44721359549995793f * 1.4426950408889634f;

    const float* src = (x == 0 ? q : (x == 1 ? k : v)) + (size_t)(bb * SEQ + s) * DIM;
    float xr[DIM];
    #pragma unroll
    for (int i = 0; i < DIM; ++i) xr[i] = src[i];

    for (int t = 0; t < 3; ++t) {
        for (int h = 0; h < H; ++h) {
            float y[DKN];
            #pragma unroll
            for (int dd = 0; dd < DKN; ++dd) {
                int j = h * DKN + dd;
                float acc = bs[t][j];
                #pragma unroll
                for (int i = 0; i < DIM; ++i) acc += xr[i] * Ws[t][j * DIM + i];
                y[dd] = acc;
            }
            float* dst = proj + proj_off(t, x, bb, h) + (size_t)s * DP;
            if (t == 0) {
                ((float4*)dst)[0] = make_float4(y[0] * QSC, y[1] * QSC, y[2] * QSC, y[3] * QSC);
                ((float4*)dst)[1] = make_float4(y[4] * QSC, 1.0f, 0.f, 0.f);   // bias dim = 1
            } else {
                ((float4*)dst)[0] = make_float4(y[0], y[1], y[2], y[3]);
                ((float4*)dst)[1] = make_float4(y[4], 0.f, 0.f, 0.f);          // bias dim = 0
            }
        }
    }
}

__global__ __launch_bounds__(256) void attn_kernel(
    const float* __restrict__ proj, const int* __restrict__ idx,
    const int* __restrict__ meta, float* __restrict__ pre)
{
    // grid linear over (p, b, h, qt): 6*8*4*4 = 768
    int lin = blockIdx.x;
    int qt  = lin & 3;  lin >>= 2;
    int h   = lin & 3;  lin >>= 2;
    int b   = lin & 7;  lin >>= 3;
    int p   = lin;
    int a   = (0x212010 >> (4 * p)) & 0xF;   // Q source
    int kv  = (0x120201 >> (4 * p)) & 0xF;   // K/V source

    const float* Qb  = proj + proj_off(0, a,  b, h);
    const float* Kb  = proj + proj_off(1, kv, b, h);
    const float* Vb  = proj + proj_off(2, kv, b, h);
    const int*  idxb = idx + b * SEQ;
    int cnt = meta[b];

    __shared__ float Ks[KT][DP];
    __shared__ float Vs[KT][DP];

    int tid = threadIdx.x;
    int sq0 = qt * 512 + tid;                // 2 queries per lane: sq0, sq0+256

    const float* q0p = Qb + (size_t)sq0 * DP;
    const float* q1p = q0p + 256 * DP;
    float4 qA0 = ((const float4*)q0p)[0], qB0 = ((const float4*)q0p)[1];
    float4 qA1 = ((const float4*)q1p)[0], qB1 = ((const float4*)q1p)[1];
    v2f q0a = {qA0.x, qA0.y}, q0b = {qA0.z, qA0.w}, q0c = {qB0.x, qB0.y}; // q[5]==1
    v2f q1a = {qA1.x, qA1.y}, q1b = {qA1.z, qA1.w}, q1c = {qB1.x, qB1.y};

    v2f o0a = {0.f, 0.f}, o0b = {0.f, 0.f};
    v2f o1a = {0.f, 0.f}, o1b = {0.f, 0.f};
    v2f o4  = {0.f, 0.f};                    // (o4_q0, o4_q1)
    v2f lp  = {0.f, 0.f};                    // (l_q0, l_q1)

    // staging roles: waves 0-1 stage K rows, waves 2-3 stage V rows (wave-uniform)
    int  stid = tid & (KT - 1);
    bool sv   = tid >= KT;
    const float* Sb = sv ? Vb : Kb;
    float* Sl = sv ? &Vs[0][0] : &Ks[0][0];

    for (int kt = 0; kt < cnt; kt += KT) {
        __syncthreads();
        {
            int key = kt + stid;
            float4 r0, r1;
            if (key < cnt) {
                const float4* src = (const float4*)(Sb + (size_t)idxb[key] * DP);
                r0 = src[0]; r1 = src[1];
            } else {
                r0 = make_float4(0.f, 0.f, 0.f, 0.f);
                // sentinel K row: bias dim = -BIG -> score -BIG -> exp2 = 0
                r1 = sv ? make_float4(0.f, 0.f, 0.f, 0.f)
                        : make_float4(0.f, NEG_BIG, 0.f, 0.f);
            }
            float4* drow = (float4*)(Sl + (size_t)stid * DP);
            drow[0] = r0; drow[1] = r1;
        }
        __syncthreads();

        #pragma unroll 8
        for (int kk = 0; kk < KT; ++kk) {
            float4 kr0 = ((const float4*)Ks[kk])[0];
            float2 kr1 = *(const float2*)&Ks[kk][4];
            float4 vr0 = ((const float4*)Vs[kk])[0];
            float  v4  = Vs[kk][4];
            v2f k01 = {kr0.x, kr0.y}, k23 = {kr0.z, kr0.w}, k45 = {kr1.x, kr1.y};
            v2f v01 = {vr0.x, vr0.y}, v23 = {vr0.z, vr0.w};

            v2f t0 = q0a * k01; t0 = q0b * k23 + t0; t0 = q0c * k45 + t0;
            v2f t1 = q1a * k01; t1 = q1b * k23 + t1; t1 = q1c * k45 + t1;
            float pe0 = EXP2(t0.x + t0.y);
            float pe1 = EXP2(t1.x + t1.y);

            v2f pp = {pe0, pe1};
            lp += pp;
            v2f bb0 = {pe0, pe0}, bb1 = {pe1, pe1};
            o0a = bb0 * v01 + o0a; o0b = bb0 * v23 + o0b;
            o1a = bb1 * v01 + o1a; o1b = bb1 * v23 + o1b;
            v2f vv4 = {v4, v4};
            o4 = pp * vv4 + o4;
        }
    }

    float inv0 = 1.0f / lp.x;
    float inv1 = 1.0f / lp.y;
    float* base = pre + (((size_t)p * B + b) * H + h) * (size_t)SEQ * DKN;
    float* d0 = base + (size_t)sq0 * DKN;
    d0[0] = o0a.x * inv0; d0[1] = o0a.y * inv0; d0[2] = o0b.x * inv0;
    d0[3] = o0b.y * inv0; d0[4] = o4.x  * inv0;
    float* d1 = d0 + 256 * DKN;
    d1[0] = o1a.x * inv1; d1[1] = o1a.y * inv1; d1[2] = o1b.x * inv1;
    d1[3] = o1b.y * inv1; d1[4] = o4.y  * inv1;
}

__global__ __launch_bounds__(256) void final_kernel(
    const float* __restrict__ pre,
    const float* __restrict__ W3, const float* __restrict__ b3,
    float* __restrict__ out)
{
    __shared__ float Ws[DIM * DIM];
    __shared__ float bs[DIM];
    int tid = threadIdx.x;
    for (int i = tid; i < DIM * DIM; i += 256) Ws[i] = W3[i];
    if (tid < DIM) bs[tid] = b3[tid];
    __syncthreads();

    int g = blockIdx.x * 256 + tid;      // B*SEQ = 16384 exactly
    int b = g / SEQ;
    int s = g - b * SEQ;

    float x[DIM];
    #pragma unroll
    for (int i = 0; i < DIM; ++i) x[i] = 0.f;

    for (int p = 0; p < 6; ++p) {
        #pragma unroll
        for (int h = 0; h < H; ++h) {
            const float* src = pre + (((size_t)p * B + b) * H + h) * (size_t)SEQ * DKN
                                   + (size_t)s * DKN;
            #pragma unroll
            for (int d = 0; d < DKN; ++d) x[h * DKN + d] += src[d];
        }
    }

    float* dst = out + (size_t)(b * SEQ + s) * DIM;
    for (int j = 0; j < DIM; ++j) {
        float acc = bs[j];
        #pragma unroll
        for (int i = 0; i < DIM; ++i) acc += x[i] * Ws[j * DIM + i];
        dst[j] = acc;
    }
}

extern "C" void kernel_launch(void* const* d_in, const int* in_sizes, int n_in,
                              void* d_out, int out_size, void* d_ws, size_t ws_size,
                              hipStream_t stream) {
    const float* q    = (const float*)d_in[0];
    const float* k    = (const float*)d_in[1];
    const float* v    = (const float*)d_in[2];
    const int*   mask = (const int*)d_in[3];
    const float* W0 = (const float*)d_in[4];  const float* b0 = (const float*)d_in[5];
    const float* W1 = (const float*)d_in[6];  const float* b1 = (const float*)d_in[7];
    const float* W2 = (const float*)d_in[8];  const float* b2 = (const float*)d_in[9];
    const float* W3 = (const float*)d_in[10]; const float* b3 = (const float*)d_in[11];

    float* proj = (float*)d_ws;                                    // 9*B*H*SEQ*DP floats
    float* pre  = proj + (size_t)9 * B * H * SEQ * DP;             // 6*B*H*SEQ*DKN floats
    int*   idx  = (int*)(pre + (size_t)6 * B * H * SEQ * DKN);     // B*SEQ ints
    int*   meta = idx + (size_t)B * SEQ;                           // B ints
    float* out  = (float*)d_out;

    compact_kernel<<<dim3(B), dim3(64), 0, stream>>>(mask, idx, meta);
    proj_kernel<<<dim3(3 * B * SEQ / 256), dim3(256), 0, stream>>>(
        q, k, v, W0, b0, W1, b1, W2, b2, proj);
    attn_kernel<<<dim3(6 * B * H * 4), dim3(256), 0, stream>>>(proj, idx, meta, pre);
    final_kernel<<<dim3(B * SEQ / 256), dim3(256), 0, stream>>>(pre, W3, b3, out);
}

// Round 4
// 249.559 us; speedup vs baseline: 2.8026x; 1.0168x over previous
//
#include <hip/hip_runtime.h>
#include <cstdint>
#include <cstddef>

#define B    8
#define SEQ  2048
#define H    4
#define DKN  5
#define DIM  20
#define PRE8 8
#define PSTRIDE 72            // LDS P-tile row stride in shorts (144B, 16B-divisible)
#define SENTB ((short)0xC6E0) // bf16(-28672): exp2(x-28672) == 0
#define ONEB  ((short)0x3F80) // bf16(1.0)

typedef short short8 __attribute__((ext_vector_type(8)));
typedef float f32x4 __attribute__((ext_vector_type(4)));

#if __has_builtin(__builtin_amdgcn_exp2f)
#define EXP2(x) __builtin_amdgcn_exp2f(x)
#else
#define EXP2(x) __expf((x) * 0.6931471805599453f)
#endif

static __device__ __forceinline__ unsigned short bf16b(float x) {
    union { float f; unsigned u; } v; v.f = x;
    unsigned r = v.u + 0x7FFFu + ((v.u >> 16) & 1u);   // round-to-nearest-even
    return (unsigned short)(r >> 16);
}
static __device__ __forceinline__ float bf16f(unsigned short h) {
    union { unsigned u; float f; } v; v.u = ((unsigned)h) << 16;
    return v.f;
}

// ws layout (shorts unless noted):
//   Qt : [x][b][h][s][16]   hi(0..7: q*QSC bf16-hi, [5]=1) | lo(8..15: bf16 residual, [5]=0)
//   Kt : [x][b][h][s][8]    compacted keys; rows >= cnt are sentinel ([5]=-28672)
//   Vt : [x][b][h][8][SEQ]  transposed compacted values; row 5 = ones (l-column trick)
//   pre: float [p][b][h][s][PRE8]
//   idx/meta: int

#define KT_ROWS   ((size_t)3 * B * H * SEQ)            // 196608 short8 rows
#define VT_CHUNKS ((size_t)3 * B * H * 8 * SEQ / 8)    // 196608 short8 chunks

// ---------------- setup: compaction (blocks 0..7) + Kt/Vt init ----------------
__global__ __launch_bounds__(256) void setup_kernel(
    const int* __restrict__ mask, int* __restrict__ idx, int* __restrict__ meta,
    short* __restrict__ Kt, short* __restrict__ Vt)
{
    int bid = blockIdx.x, tid = threadIdx.x;
    if (bid < B) {
        if (tid >= 64) return;
        int lane = tid;
        const int* m = mask + bid * SEQ;
        int* out = idx + bid * SEQ;
        int base = 0;
        for (int c = 0; c < SEQ; c += 64) {
            int v = m[c + lane];
            unsigned long long bal = __ballot(v != 0);
            int pre = __popcll(bal & ((1ull << lane) - 1ull));
            if (v) out[base + pre] = c + lane;
            base += (int)__popcll(bal);
        }
        if (lane == 0) meta[bid] = base;
        return;
    }
    int slot = (bid - B) * 256 + tid;
    if (slot < (int)KT_ROWS) {
        short8 r = {0, 0, 0, 0, 0, SENTB, 0, 0};
        ((short8*)Kt)[slot] = r;
    } else {
        int vs = slot - (int)KT_ROWS;            // < VT_CHUNKS
        int n = (vs >> 8) & 7;                   // SEQ/8 = 256 chunks per n-row
        short8 zer = {0, 0, 0, 0, 0, 0, 0, 0};
        short8 one = {ONEB, ONEB, ONEB, ONEB, ONEB, ONEB, ONEB, ONEB};
        ((short8*)Vt)[vs] = (n == 5) ? one : zer;
    }
}

// ---------------- projections ----------------
__global__ __launch_bounds__(256) void proj_kernel(
    const float* __restrict__ q, const float* __restrict__ k, const float* __restrict__ v,
    const float* __restrict__ W0, const float* __restrict__ b0,
    const float* __restrict__ W1, const float* __restrict__ b1,
    const float* __restrict__ W2, const float* __restrict__ b2,
    const int* __restrict__ idx, const int* __restrict__ meta,
    short* __restrict__ Qt, short* __restrict__ Kt, short* __restrict__ Vt)
{
    __shared__ float Ws[3][DIM * DIM];
    __shared__ float bsh[3][DIM];
    int tid = threadIdx.x;
    for (int i = tid; i < DIM * DIM; i += 256) {
        Ws[0][i] = W0[i]; Ws[1][i] = W1[i]; Ws[2][i] = W2[i];
    }
    if (tid < DIM) { bsh[0][tid] = b0[tid]; bsh[1][tid] = b1[tid]; bsh[2][tid] = b2[tid]; }
    __syncthreads();

    int g   = blockIdx.x * 256 + tid;     // 3*B*SEQ = 49152 exactly
    int x   = g / (B * SEQ);
    int rem = g - x * (B * SEQ);
    int bb  = rem / SEQ;
    int s   = rem - bb * SEQ;

    const float QSC = 0.44721359549995793f * 1.4426950408889634f;  // (1/sqrt5)*log2(e)
    const float* base = (x == 0) ? q : ((x == 1) ? k : v);

    float xq[DIM];
    {
        const float* xr = base + (size_t)(bb * SEQ + s) * DIM;
        #pragma unroll
        for (int i = 0; i < DIM; ++i) xq[i] = xr[i];
    }
    int  cnt   = meta[bb];
    bool valid = s < cnt;
    int  gs    = valid ? idx[bb * SEQ + s] : 0;
    float xg[DIM];
    {
        const float* xr = base + (size_t)(bb * SEQ + gs) * DIM;
        #pragma unroll
        for (int i = 0; i < DIM; ++i) xg[i] = xr[i];
    }

    #define DOT20(xv, t, j, dst) {                                        \
        float acc_ = bsh[t][j];                                           \
        const float4* wr_ = (const float4*)&Ws[t][(j) * DIM];             \
        _Pragma("unroll")                                                 \
        for (int i4 = 0; i4 < 5; ++i4) {                                  \
            float4 w_ = wr_[i4];                                          \
            acc_ += (xv)[i4*4+0]*w_.x + (xv)[i4*4+1]*w_.y                 \
                  + (xv)[i4*4+2]*w_.z + (xv)[i4*4+3]*w_.w;                \
        }                                                                 \
        dst = acc_;                                                       \
    }

    size_t rowbase = ((size_t)(x * B + bb) * H) * SEQ;
    #pragma unroll
    for (int h = 0; h < H; ++h) {
        size_t row = rowbase + (size_t)h * SEQ + s;

        // Q-role (W0): pre-scaled, hi/lo bf16 split; hi[5]=1 (bias), lo[5]=0
        short8 qhi = {0, 0, 0, 0, 0, ONEB, 0, 0};
        short8 qlo = {0, 0, 0, 0, 0, 0, 0, 0};
        #pragma unroll
        for (int d = 0; d < DKN; ++d) {
            float y; DOT20(xq, 0, h * DKN + d, y);
            y *= QSC;
            unsigned short hb = bf16b(y);
            qhi[d] = (short)hb;
            qlo[d] = (short)bf16b(y - bf16f(hb));
        }
        ((short8*)Qt)[row * 2 + 0] = qhi;
        ((short8*)Qt)[row * 2 + 1] = qlo;

        if (valid) {
            // K-role (W1) on gathered key row; [5]=0 (real key)
            short8 rk = {0, 0, 0, 0, 0, 0, 0, 0};
            #pragma unroll
            for (int d = 0; d < DKN; ++d) {
                float y; DOT20(xg, 1, h * DKN + d, y);
                rk[d] = (short)bf16b(y);
            }
            ((short8*)Kt)[row] = rk;

            // V-role (W2), transposed: Vt[n=d][c=s]
            size_t vb = ((size_t)(x * B + bb) * H + h) * 8 * SEQ;
            #pragma unroll
            for (int d = 0; d < DKN; ++d) {
                float y; DOT20(xg, 2, h * DKN + d, y);
                Vt[vb + (size_t)d * SEQ + s] = (short)bf16b(y);
            }
        }
    }
}

// ---------------- MFMA flash attention (bf16, verified layouts) ----------------
__global__ __launch_bounds__(256) void attn_kernel(
    const short* __restrict__ Qt, const short* __restrict__ Kt,
    const short* __restrict__ Vt, const int* __restrict__ meta,
    float* __restrict__ pre)
{
    __shared__ short Ptile[4][16 * PSTRIDE];

    int tid  = threadIdx.x;
    int wave = tid >> 6, lane = tid & 63;
    int col  = lane & 15, quad = lane >> 4;

    int lin = blockIdx.x;          // 6*8*4*32 = 6144
    int qt  = lin & 31; lin >>= 5;
    int h   = lin & 3;  lin >>= 2;
    int b   = lin & 7;  lin >>= 3;
    int p   = lin;
    int a   = (0x212010 >> (4 * p)) & 0xF;   // Q source
    int kv  = (0x120201 >> (4 * p)) & 0xF;   // K/V source

    const short*  Qb = Qt + ((size_t)(a  * B + b) * H + h) * SEQ * 16;
    const short8* Kb = (const short8*)Kt + ((size_t)(kv * B + b) * H + h) * SEQ;
    const short*  Vb = Vt + ((size_t)(kv * B + b) * H + h) * 8 * SEQ;

    int cnt  = meta[b];
    int kend = (cnt + 63) & ~63;

    int qbase = qt * 64 + wave * 16;
    // A-frag: A[m=col][k=quad*8+j]. quad0 = Q-hi (k 0..7), quad1 = Q-lo (k 8..15).
    short8 qf = {0, 0, 0, 0, 0, 0, 0, 0};
    if (quad < 2) qf = *(const short8*)(Qb + (size_t)(qbase + col) * 16 + quad * 8);

    short* Pl = Ptile[wave];
    f32x4 acc = {0.f, 0.f, 0.f, 0.f};
    f32x4 zc  = {0.f, 0.f, 0.f, 0.f};
    int vrow = col & 7;   // Vt has 8 rows; cols 8..15 duplicate (acc cols 8..15 unused)

    for (int c0 = 0; c0 < kend; c0 += 64) {
        // B-frag for scores: B[n=key][k]; quads 0 AND 1 load the SAME K chunk
        // (k-duplication implements hi*K + lo*K = fp32-accurate Q dot K).
        short8 kf0 = {0,0,0,0,0,0,0,0}, kf1 = kf0, kf2 = kf0, kf3 = kf0;
        if (quad < 2) {
            kf0 = Kb[c0 + col];
            kf1 = Kb[c0 + 16 + col];
            kf2 = Kb[c0 + 32 + col];
            kf3 = Kb[c0 + 48 + col];
        }
        f32x4 s0 = __builtin_amdgcn_mfma_f32_16x16x32_bf16(qf, kf0, zc, 0, 0, 0);
        f32x4 s1 = __builtin_amdgcn_mfma_f32_16x16x32_bf16(qf, kf1, zc, 0, 0, 0);
        f32x4 s2 = __builtin_amdgcn_mfma_f32_16x16x32_bf16(qf, kf2, zc, 0, 0, 0);
        f32x4 s3 = __builtin_amdgcn_mfma_f32_16x16x32_bf16(qf, kf3, zc, 0, 0, 0);

        __syncthreads();   // WAR: previous iteration's P reads complete
        // C/D layout: col=lane&15 = key-within-16, row=quad*4+r = q
        int wb = (quad * 4) * PSTRIDE + col;
        #pragma unroll
        for (int r = 0; r < 4; ++r) {
            Pl[wb + r * PSTRIDE +  0] = (short)bf16b(EXP2(s0[r]));
            Pl[wb + r * PSTRIDE + 16] = (short)bf16b(EXP2(s1[r]));
            Pl[wb + r * PSTRIDE + 32] = (short)bf16b(EXP2(s2[r]));
            Pl[wb + r * PSTRIDE + 48] = (short)bf16b(EXP2(s3[r]));
        }
        __syncthreads();   // make P visible

        // A-frag: P[m=q=col][k=key=quad*8+j]
        short8 pf0 = *(const short8*)(Pl + col * PSTRIDE + quad * 8);
        short8 pf1 = *(const short8*)(Pl + col * PSTRIDE + 32 + quad * 8);
        // B-frag: Vt[n=vdim][k=key]; row 5 = ones -> acc col 5 = softmax denom l
        short8 vf0 = *(const short8*)(Vb + (size_t)vrow * SEQ + c0 + quad * 8);
        short8 vf1 = *(const short8*)(Vb + (size_t)vrow * SEQ + c0 + 32 + quad * 8);

        acc = __builtin_amdgcn_mfma_f32_16x16x32_bf16(pf0, vf0, acc, 0, 0, 0);
        acc = __builtin_amdgcn_mfma_f32_16x16x32_bf16(pf1, vf1, acc, 0, 0, 0);
    }

    float* prow = pre + (((size_t)p * B + b) * H + h) * SEQ * PRE8 + (size_t)qbase * PRE8;
    #pragma unroll
    for (int r = 0; r < 4; ++r) {
        float lv = __shfl(acc[r], (lane & 48) | 5, 64);
        float ov = acc[r] / lv;
        if (col < DKN) prow[(quad * 4 + r) * PRE8 + col] = ov;
    }
}

// ---------------- sum 6 pairs + output projection ----------------
__global__ __launch_bounds__(256) void final_kernel(
    const float* __restrict__ pre,
    const float* __restrict__ W3, const float* __restrict__ b3,
    float* __restrict__ out)
{
    __shared__ float Ws[DIM * DIM];
    __shared__ float bs[DIM];
    int tid = threadIdx.x;
    for (int i = tid; i < DIM * DIM; i += 256) Ws[i] = W3[i];
    if (tid < DIM) bs[tid] = b3[tid];
    __syncthreads();

    int g = blockIdx.x * 256 + tid;      // B*SEQ = 16384 exactly
    int b = g / SEQ;
    int s = g - b * SEQ;

    float x[DIM];
    #pragma unroll
    for (int i = 0; i < DIM; ++i) x[i] = 0.f;

    for (int p = 0; p < 6; ++p) {
        #pragma unroll
        for (int h = 0; h < H; ++h) {
            const float* sr = pre + (((size_t)p * B + b) * H + h) * SEQ * PRE8
                                  + (size_t)s * PRE8;
            float4 a = *(const float4*)sr;
            float  a4 = sr[4];
            x[h * DKN + 0] += a.x; x[h * DKN + 1] += a.y; x[h * DKN + 2] += a.z;
            x[h * DKN + 3] += a.w; x[h * DKN + 4] += a4;
        }
    }

    float y[DIM];
    for (int j = 0; j < DIM; ++j) {
        float acc = bs[j];
        const float4* wr = (const float4*)&Ws[j * DIM];
        #pragma unroll
        for (int i4 = 0; i4 < 5; ++i4) {
            float4 w = wr[i4];
            acc += x[i4*4+0]*w.x + x[i4*4+1]*w.y + x[i4*4+2]*w.z + x[i4*4+3]*w.w;
        }
        y[j] = acc;
    }
    float4* dst = (float4*)(out + (size_t)(b * SEQ + s) * DIM);
    #pragma unroll
    for (int j4 = 0; j4 < 5; ++j4)
        dst[j4] = make_float4(y[j4*4+0], y[j4*4+1], y[j4*4+2], y[j4*4+3]);
}

extern "C" void kernel_launch(void* const* d_in, const int* in_sizes, int n_in,
                              void* d_out, int out_size, void* d_ws, size_t ws_size,
                              hipStream_t stream) {
    const float* q    = (const float*)d_in[0];
    const float* k    = (const float*)d_in[1];
    const float* v    = (const float*)d_in[2];
    const int*   mask = (const int*)d_in[3];
    const float* W0 = (const float*)d_in[4];  const float* b0 = (const float*)d_in[5];
    const float* W1 = (const float*)d_in[6];  const float* b1 = (const float*)d_in[7];
    const float* W2 = (const float*)d_in[8];  const float* b2 = (const float*)d_in[9];
    const float* W3 = (const float*)d_in[10]; const float* b3 = (const float*)d_in[11];

    short* Qt = (short*)d_ws;                                // 3*B*H*SEQ*16 shorts (6 MB)
    short* Kt = Qt + (size_t)3 * B * H * SEQ * 16;           // 3*B*H*SEQ*8  shorts (3 MB)
    short* Vt = Kt + (size_t)3 * B * H * SEQ * 8;            // 3*B*H*8*SEQ  shorts (3 MB)
    float* pre = (float*)(Vt + (size_t)3 * B * H * 8 * SEQ); // 6*B*H*SEQ*8 floats (12.6 MB)
    int*   idx = (int*)(pre + (size_t)6 * B * H * SEQ * PRE8);
    int*   meta = idx + (size_t)B * SEQ;
    float* out = (float*)d_out;

    int init_blocks = (int)((KT_ROWS + VT_CHUNKS + 255) / 256);   // 1536
    setup_kernel<<<dim3(B + init_blocks), dim3(256), 0, stream>>>(mask, idx, meta, Kt, Vt);
    proj_kernel<<<dim3(3 * B * SEQ / 256), dim3(256), 0, stream>>>(
        q, k, v, W0, b0, W1, b1, W2, b2, idx, meta, Qt, Kt, Vt);
    attn_kernel<<<dim3(6 * B * H * 32), dim3(256), 0, stream>>>(Qt, Kt, Vt, meta, pre);
    final_kernel<<<dim3(B * SEQ / 256), dim3(256), 0, stream>>>(pre, W3, b3, out);
}